// Round 15
// baseline (283.353 us; speedup 1.0000x reference)
//
#include <hip/hip_runtime.h>
#include <hip/hip_bf16.h>

#define NTOT (4*256*256)      // 262144 feature rows
#define DIM 384
#define KCL 256               // clusters
#define BM 64                 // rows per block tile
#define TBS 256
#define GRID_MAIN (NTOT/BM)   // 4096 blocks
#define NT 12                 // K-steps of 32
#define EPS 1e-12f
#define DELTA 1e-3f           // fp16 gap rescue margin (~25 sigma, Hoeffding e^-208)
#define RBLK 512              // rescue blocks
#define WPB (GRID_MAIN/RBLK)  // flag words per rescue block = 8

// LDS main: A hi double-buffer, 2 x 4 KiB
#define SMEM_BYTES 8192

typedef __attribute__((ext_vector_type(8))) _Float16 f16x8;
typedef __attribute__((ext_vector_type(4))) float f32x4;

// ---------------------------------------------------------------------------
// Pre-pass: L2-normalize clusters; emit fp16 hi in FRAGMENT ORDER
// (j,d) -> ((((t*4+w)*4+n)*4+g)*16+nl)*8+d0  [proven R9-R14] and invn[j].
// ---------------------------------------------------------------------------
__global__ void prep_clusters(const float* __restrict__ cc,
                              _Float16* __restrict__ bh,
                              float* __restrict__ invn) {
    int j = blockIdx.x, l = threadIdx.x;   // 256 blocks x 64 lanes
    float v[6]; float ssq = 0.f;
#pragma unroll
    for (int i = 0; i < 6; ++i) { v[i] = cc[j*DIM + l + 64*i]; ssq = fmaf(v[i], v[i], ssq); }
#pragma unroll
    for (int off = 32; off >= 1; off >>= 1) ssq += __shfl_xor(ssq, off);
    float inv = 1.f / fmaxf(sqrtf(ssq), EPS);
    if (l == 0) invn[j] = inv;
    const int w = j >> 6, n = (j >> 4) & 3, nl = j & 15;
#pragma unroll
    for (int i = 0; i < 6; ++i) {
        int d = l + 64 * i;
        size_t idx = (size_t)((((((d >> 5)*4 + w)*4 + n)*4 + ((d >> 3) & 3))*16 + nl)*8
                              + (d & 7));
        bh[idx] = (_Float16)(v[i] * inv);
    }
}

// ---------------------------------------------------------------------------
// Main: 1-pass fp16 MFMA GEMM on the R12 skeleton (16 MFMA/step), top-2
// epilogue, ambiguous rows (gap < DELTA) flagged via ballot and EXCLUDED
// from the loss partial (rescue adds their exact terms).
// ---------------------------------------------------------------------------
__global__ __launch_bounds__(TBS, 3)
void kmeans_main(const float* __restrict__ A,    // [NTOT][384] f32
                 const float* __restrict__ W,    // [NTOT]
                 const _Float16* __restrict__ Bh,// fragment-order fp16 hi
                 const int*   __restrict__ PA,   // [256]
                 float* __restrict__ out,        // [2*NTOT+1]
                 float* __restrict__ partial,    // [GRID_MAIN]
                 unsigned long long* __restrict__ flags) // [GRID_MAIN]
{
    __shared__ unsigned char smem[SMEM_BYTES];

    const int tid  = threadIdx.x;
    const int wv   = tid >> 6;        // wave -> cluster quarter [64wv, 64wv+64)
    const int lane = tid & 63;
    const int g    = lane >> 4;
    const int l15  = lane & 15;
    const int sw   = (l15 >> 1) & 3;  // A read-side swizzle (proven 0-conflict)
    const int row0 = blockIdx.x * BM;
    const int arow = tid >> 2, achk = tid & 3;
    const int awb  = (((arow << 2) + (achk ^ ((arow >> 1) & 3))) << 4);
    const int fa   = l15 * 64 + ((g ^ sw) << 4);      // A frag base (+m*1024)

    const float* ap = A + (size_t)(row0 + arow) * DIM + achk * 8;
    const unsigned char* bsh = (const unsigned char*)Bh + (size_t)(wv * 4) * 1024 + lane * 16;

    f32x4 acc[4][4];
#pragma unroll
    for (int m = 0; m < 4; ++m)
#pragma unroll
        for (int n = 0; n < 4; ++n) acc[m][n] = (f32x4){0.f, 0.f, 0.f, 0.f};
    float ssq = 0.f;

    f16x8  bfh[4];               // current B fragments
    float4 sA[2][2];             // A f32 prefetch slots by tile parity

    auto LDA = [&](int s, int tt) {
        sA[s][0] = *(const float4*)(ap + tt * 32);
        sA[s][1] = *(const float4*)(ap + tt * 32 + 4);
    };
    auto LDBH = [&](int tt) {
#pragma unroll
        for (int n = 0; n < 4; ++n)
            bfh[n] = *(const f16x8*)(bsh + (size_t)(tt * 16 + n) * 1024);
    };
    auto CVTW = [&](int s, int p) {
        float av[8] = {sA[s][0].x, sA[s][0].y, sA[s][0].z, sA[s][0].w,
                       sA[s][1].x, sA[s][1].y, sA[s][1].z, sA[s][1].w};
        f16x8 h8;
#pragma unroll
        for (int e = 0; e < 8; ++e) {
            h8[e] = (_Float16)av[e];
            ssq = fmaf(av[e], av[e], ssq);
        }
        *(f16x8*)(smem + p * 4096 + awb) = h8;
    };

    // ---- prologue ----
    LDA(0, 0);
    LDBH(0);
    LDA(1, 1);
    CVTW(0, 0);
    asm volatile("s_waitcnt lgkmcnt(0)" ::: "memory");
    __builtin_amdgcn_s_barrier();

    // ---- main loop (R12-proven schedule, hh pass only) ----
#pragma unroll
    for (int t = 0; t < NT; ++t) {
        if (t + 2 < NT) LDA((t + 2) & 1, t + 2);

        f16x8 ahf[4];
#pragma unroll
        for (int m = 0; m < 4; ++m)
            ahf[m] = *(const f16x8*)(smem + (t & 1) * 4096 + fa + m * 1024);
        if (t + 1 < NT) CVTW((t + 1) & 1, (t + 1) & 1);
        asm volatile("s_waitcnt lgkmcnt(0)" ::: "memory");
        __builtin_amdgcn_s_barrier();

        __builtin_amdgcn_s_setprio(1);
#pragma unroll
        for (int m = 0; m < 4; ++m)
#pragma unroll
            for (int n = 0; n < 4; ++n)
                acc[m][n] = __builtin_amdgcn_mfma_f32_16x16x32_f16(ahf[m], bfh[n], acc[m][n], 0, 0, 0);
        __builtin_amdgcn_s_setprio(0);
        if (t + 1 < NT) LDBH(t + 1);
    }
    __syncthreads();

    // ---- epilogue: top-2 per row, flags, loss partial ----
    float* rowssq = (float*)smem;                  // 256 B
    float* wvalp  = (float*)(smem + 256);          // 1 KiB
    float* wsecp  = (float*)(smem + 1280);         // 1 KiB
    int*   wcolp  = (int*)(smem + 2304);           // 1 KiB

    ssq += __shfl_xor(ssq, 1);
    ssq += __shfl_xor(ssq, 2);
    if (achk == 0) rowssq[arow] = ssq;

    // per-row top-2 over this wave's 64 cols. acc[m][n][j]=S[16m+4g+j][64wv+16n+l15]
#pragma unroll
    for (int m = 0; m < 4; ++m) {
#pragma unroll
        for (int j = 0; j < 4; ++j) {
            float b0 = acc[m][0][j]; int i0 = 64*wv + l15; float s0 = -3.0e38f;
#pragma unroll
            for (int n = 1; n < 4; ++n) {
                float v = acc[m][n][j]; int c = 64*wv + 16*n + l15;
                if (v > b0) { s0 = b0; b0 = v; i0 = c; } else { s0 = fmaxf(s0, v); }
            }
#pragma unroll
            for (int off = 1; off < 16; off <<= 1) {
                float ov = __shfl_xor(b0, off);
                int   oi = __shfl_xor(i0, off);
                float os = __shfl_xor(s0, off);
                if (ov > b0 || (ov == b0 && oi < i0)) { s0 = fmaxf(os, b0); b0 = ov; i0 = oi; }
                else                                  { s0 = fmaxf(s0, ov); }
            }
            if (l15 == 0) {
                int r = 16*m + 4*g + j;
                wvalp[wv * BM + r] = b0; wsecp[wv * BM + r] = s0; wcolp[wv * BM + r] = i0;
            }
        }
    }
    __syncthreads();

    if (tid < BM) {
        int r = tid;
        float b = wvalp[r], s = wsecp[r]; int i = wcolp[r];
#pragma unroll
        for (int w = 1; w < 4; ++w) {
            float bw = wvalp[w * BM + r], sw2 = wsecp[w * BM + r]; int iw = wcolp[w * BM + r];
            if (bw > b || (bw == b && iw < i)) { s = fmaxf(b, sw2); b = bw; i = iw; }
            else                               { s = fmaxf(s, bw); }
        }
        float inv = 1.f / fmaxf(sqrtf(rowssq[r]), EPS);
        int gr = row0 + r;
        out[gr]        = (float)i;
        out[NTOT + gr] = (float)PA[i];
        bool amb = (b - s) < DELTA;
        unsigned long long mask = __ballot(amb);
        float lsum = amb ? 0.f : -(b * inv) * W[gr];
#pragma unroll
        for (int off = 32; off >= 1; off >>= 1) lsum += __shfl_xor(lsum, off);
        if (tid == 0) { partial[blockIdx.x] = lsum; flags[blockIdx.x] = mask; }
    }
}

// ---------------------------------------------------------------------------
// Exact f32 rescue: each of RBLK blocks scans its WPB flag words, gathers
// rows (max 64*WPB = exactly rlist capacity), rescored exactly:
// score_j = (sum_d a_d * cc[j][d]) * invn[j]. Deterministic (no atomics).
// ---------------------------------------------------------------------------
__global__ __launch_bounds__(256)
void rescue(const float* __restrict__ A, const float* __restrict__ W,
            const float* __restrict__ cc, const float* __restrict__ invn,
            const unsigned long long* __restrict__ flags,
            const int* __restrict__ PA,
            float* __restrict__ out, float* __restrict__ partial2)
{
    __shared__ float rows[4][8][DIM];   // 48 KiB
    __shared__ int   rlist[64 * WPB];   // 512 entries, 2 KiB (cannot overflow)
    __shared__ int   rcount;
    __shared__ float wsum[4];
    const int tid = threadIdx.x, wv = tid >> 6, lane = tid & 63;
    const int b = blockIdx.x;

    if (tid == 0) {
        int c = 0;
#pragma unroll
        for (int w = 0; w < WPB; ++w) {
            unsigned long long m = flags[b * WPB + w];
            while (m) {
                int bit = __ffsll((long long)m) - 1;
                m &= m - 1;
                rlist[c++] = (b * WPB + w) * 64 + bit;
            }
        }
        rcount = c;
    }
    __syncthreads();
    const int nb = rcount;
    const float in0 = invn[lane], in1 = invn[64 + lane],
                in2 = invn[128 + lane], in3 = invn[192 + lane];
    float lacc = 0.f;
    const int nbatch = (nb + 31) >> 5;       // 32 rows per batch (4 waves x 8)

    for (int bt = 0; bt < nbatch; ++bt) {
        const int base = bt * 32 + wv * 8;
        int rIdx[8]; float ssq8[8];
#pragma unroll
        for (int i = 0; i < 8; ++i) {
            int li = base + i;
            int r = rlist[li < nb ? li : 0];  // nb>=1 inside loop
            rIdx[i] = r;
            float ps = 0.f;
#pragma unroll
            for (int c = 0; c < 6; ++c) {
                float x = A[(size_t)r * DIM + c*64 + lane];
                rows[wv][i][c*64 + lane] = x;
                ps = fmaf(x, x, ps);
            }
#pragma unroll
            for (int off = 32; off >= 1; off >>= 1) ps += __shfl_xor(ps, off);
            ssq8[i] = ps;
        }
        __syncthreads();
        float d0[8], d1[8], d2[8], d3[8];
#pragma unroll
        for (int i = 0; i < 8; ++i) { d0[i]=0.f; d1[i]=0.f; d2[i]=0.f; d3[i]=0.f; }
#pragma unroll 4
        for (int k = 0; k < DIM; k += 4) {
            float4 rv[8];
#pragma unroll
            for (int i = 0; i < 8; ++i) rv[i] = *(const float4*)&rows[wv][i][k];
            float4 c0 = *(const float4*)&cc[(size_t)(0*64 + lane)*DIM + k];
            float4 c1 = *(const float4*)&cc[(size_t)(1*64 + lane)*DIM + k];
            float4 c2 = *(const float4*)&cc[(size_t)(2*64 + lane)*DIM + k];
            float4 c3 = *(const float4*)&cc[(size_t)(3*64 + lane)*DIM + k];
#pragma unroll
            for (int i = 0; i < 8; ++i) {
                d0[i] = fmaf(c0.x,rv[i].x, fmaf(c0.y,rv[i].y, fmaf(c0.z,rv[i].z, fmaf(c0.w,rv[i].w, d0[i]))));
                d1[i] = fmaf(c1.x,rv[i].x, fmaf(c1.y,rv[i].y, fmaf(c1.z,rv[i].z, fmaf(c1.w,rv[i].w, d1[i]))));
                d2[i] = fmaf(c2.x,rv[i].x, fmaf(c2.y,rv[i].y, fmaf(c2.z,rv[i].z, fmaf(c2.w,rv[i].w, d2[i]))));
                d3[i] = fmaf(c3.x,rv[i].x, fmaf(c3.y,rv[i].y, fmaf(c3.z,rv[i].z, fmaf(c3.w,rv[i].w, d3[i]))));
            }
        }
#pragma unroll
        for (int i = 0; i < 8; ++i) {
            if (base + i < nb) {
                float v0 = d0[i]*in0, v1 = d1[i]*in1, v2 = d2[i]*in2, v3 = d3[i]*in3;
                float best = v0; int bj = lane;
                { if (v1 > best) { best = v1; bj = 64 + lane; } }
                { if (v2 > best) { best = v2; bj = 128 + lane; } }
                { if (v3 > best) { best = v3; bj = 192 + lane; } }
#pragma unroll
                for (int off = 1; off < 64; off <<= 1) {
                    float ov = __shfl_xor(best, off);
                    int   oj = __shfl_xor(bj, off);
                    if (ov > best || (ov == best && oj < bj)) { best = ov; bj = oj; }
                }
                if (lane == 0) {
                    int r = rIdx[i];
                    float inva = 1.f / fmaxf(sqrtf(ssq8[i]), EPS);
                    out[r]        = (float)bj;
                    out[NTOT + r] = (float)PA[bj];
                    lacc = fmaf(-(best * inva), W[r], lacc);
                }
            }
        }
        __syncthreads();
    }
    if (lane == 0) wsum[wv] = lacc;
    __syncthreads();
    if (tid == 0) partial2[b] = ((wsum[0] + wsum[1]) + (wsum[2] + wsum[3]));
}

// ---------------------------------------------------------------------------
// Deterministic loss reduction: 4096 main partials + RBLK rescue partials
// ---------------------------------------------------------------------------
__global__ void loss_reduce(const float* __restrict__ partial,
                            const float* __restrict__ partial2,
                            float* __restrict__ out_loss) {
    __shared__ float s[256];
    const int t = threadIdx.x;
    float v = 0.f;
    for (int i = t; i < GRID_MAIN; i += 256) v += partial[i];
    for (int i = t; i < RBLK; i += 256) v += partial2[i];
    s[t] = v;
    __syncthreads();
    for (int off = 128; off >= 1; off >>= 1) {
        if (t < off) s[t] += s[t + off];
        __syncthreads();
    }
    if (t == 0) out_loss[0] = s[0] * (1.0f / (float)NTOT);
}

extern "C" void kernel_launch(void* const* d_in, const int* in_sizes, int n_in,
                              void* d_out, int out_size, void* d_ws, size_t ws_size,
                              hipStream_t stream) {
    const float* features = (const float*)d_in[0];
    const float* weight   = (const float*)d_in[1];
    const float* cc       = (const float*)d_in[2];
    const int*   pa       = (const int*)d_in[3];
    float* out = (float*)d_out;

    // ws layout (total ~243 KiB, well under the ~400 KiB proven-safe budget)
    _Float16* bh = (_Float16*)d_ws;                          // 192 KiB
    unsigned long long* flags = (unsigned long long*)(bh + KCL * DIM); // 32 KiB (8-aligned)
    float* invn    = (float*)(flags + GRID_MAIN);            // 1 KiB
    float* partial = invn + KCL;                             // 16 KiB
    float* partial2 = partial + GRID_MAIN;                   // 2 KiB

    hipLaunchKernelGGL(prep_clusters, dim3(KCL), dim3(64), 0, stream, cc, bh, invn);
    hipLaunchKernelGGL(kmeans_main, dim3(GRID_MAIN), dim3(TBS), 0, stream,
                       features, weight, bh, pa, out, partial, flags);
    hipLaunchKernelGGL(rescue, dim3(RBLK), dim3(256), 0, stream,
                       features, weight, cc, invn, flags, pa, out, partial2);
    hipLaunchKernelGGL(loss_reduce, dim3(1), dim3(256), 0, stream,
                       partial, partial2, out + 2 * NTOT);
}

// Round 16
// 208.121 us; speedup vs baseline: 1.3615x; 1.3615x over previous
//
#include <hip/hip_runtime.h>
#include <hip/hip_bf16.h>

#define NTOT (4*256*256)      // 262144 feature rows
#define DIM 384
#define KCL 256               // clusters
#define BM 64                 // rows per block tile
#define TBS 256
#define GRID_MAIN (NTOT/BM)   // 4096 blocks
#define NT 12                 // K-steps of 32
#define EPS 1e-12f
// Rescue margin (RAW score units, score std ~= 1.0):
// |score_fp16 - score_f32| <= 2^-10 * ||a||; ||a||_max ~= 23.5 over all rows
// -> errmax <= 0.023. DELTA = 0.09 > 2*errmax with ~2x margin (provable).
#define DELTA 0.09f
#define CAP 12                // candidate-list capacity (window count ~Poisson(0.25))

#define SMEM_BYTES 8192       // A hi double-buffer 2 x 4 KiB; epilogue overlays

typedef __attribute__((ext_vector_type(8))) _Float16 f16x8;
typedef __attribute__((ext_vector_type(4))) float f32x4;

// ---------------------------------------------------------------------------
// Pre-pass: L2-normalize clusters; fp16 hi in FRAGMENT ORDER
// (j,d) -> ((((t*4+w)*4+n)*4+g)*16+nl)*8+d0  [proven R9-R15]; invn[j] = 1/||cc_j||.
// ---------------------------------------------------------------------------
__global__ void prep_clusters(const float* __restrict__ cc,
                              _Float16* __restrict__ bh,
                              float* __restrict__ invn) {
    int j = blockIdx.x, l = threadIdx.x;   // 256 blocks x 64 lanes
    float v[6]; float ssq = 0.f;
#pragma unroll
    for (int i = 0; i < 6; ++i) { v[i] = cc[j*DIM + l + 64*i]; ssq = fmaf(v[i], v[i], ssq); }
#pragma unroll
    for (int off = 32; off >= 1; off >>= 1) ssq += __shfl_xor(ssq, off);
    float inv = 1.f / fmaxf(sqrtf(ssq), EPS);
    if (l == 0) invn[j] = inv;
    const int w = j >> 6, n = (j >> 4) & 3, nl = j & 15;
#pragma unroll
    for (int i = 0; i < 6; ++i) {
        int d = l + 64 * i;
        size_t idx = (size_t)((((((d >> 5)*4 + w)*4 + n)*4 + ((d >> 3) & 3))*16 + nl)*8
                              + (d & 7));
        bh[idx] = (_Float16)(v[i] * inv);
    }
}

// ---------------------------------------------------------------------------
// Main: 1-pass fp16 MFMA GEMM (R15-proven loop) at 4 waves/SIMD, plus
// in-epilogue PROVABLE exact rescue: flag gap<DELTA rows, static-scan acc for
// candidate cols within DELTA of top1, rescore candidates exactly in f32 with
// coalesced wave-dots, argmax(exact) with first-index tie-break.
// ---------------------------------------------------------------------------
__global__ __launch_bounds__(TBS, 4)
void kmeans_main(const float* __restrict__ A,    // [NTOT][384] f32
                 const float* __restrict__ W,    // [NTOT]
                 const _Float16* __restrict__ Bh,// fragment-order fp16 hi
                 const float* __restrict__ cc,   // raw clusters f32 (rescue)
                 const float* __restrict__ invn, // [256] 1/||cc_j||
                 const int*   __restrict__ PA,   // [256]
                 float* __restrict__ out,        // [2*NTOT+1]
                 float* __restrict__ partial)    // [GRID_MAIN]
{
    __shared__ unsigned char smem[SMEM_BYTES];

    const int tid  = threadIdx.x;
    const int wv   = tid >> 6;        // wave -> cluster quarter [64wv, 64wv+64)
    const int lane = tid & 63;
    const int g    = lane >> 4;
    const int l15  = lane & 15;
    const int sw   = (l15 >> 1) & 3;  // A read-side swizzle (proven 0-conflict)
    const int row0 = blockIdx.x * BM;
    const int arow = tid >> 2, achk = tid & 3;
    const int awb  = (((arow << 2) + (achk ^ ((arow >> 1) & 3))) << 4);
    const int fa   = l15 * 64 + ((g ^ sw) << 4);      // A frag base (+m*1024)

    const float* ap = A + (size_t)(row0 + arow) * DIM + achk * 8;
    const unsigned char* bsh = (const unsigned char*)Bh + (size_t)(wv * 4) * 1024 + lane * 16;

    f32x4 acc[4][4];
#pragma unroll
    for (int m = 0; m < 4; ++m)
#pragma unroll
        for (int n = 0; n < 4; ++n) acc[m][n] = (f32x4){0.f, 0.f, 0.f, 0.f};
    float ssq = 0.f;

    f16x8  bfh[4];
    float4 sA[2][2];

    auto LDA = [&](int s, int tt) {
        sA[s][0] = *(const float4*)(ap + tt * 32);
        sA[s][1] = *(const float4*)(ap + tt * 32 + 4);
    };
    auto LDBH = [&](int tt) {
#pragma unroll
        for (int n = 0; n < 4; ++n)
            bfh[n] = *(const f16x8*)(bsh + (size_t)(tt * 16 + n) * 1024);
    };
    auto CVTW = [&](int s, int p) {
        float av[8] = {sA[s][0].x, sA[s][0].y, sA[s][0].z, sA[s][0].w,
                       sA[s][1].x, sA[s][1].y, sA[s][1].z, sA[s][1].w};
        f16x8 h8;
#pragma unroll
        for (int e = 0; e < 8; ++e) {
            h8[e] = (_Float16)av[e];
            ssq = fmaf(av[e], av[e], ssq);
        }
        *(f16x8*)(smem + p * 4096 + awb) = h8;
    };

    // ---- prologue ----
    LDA(0, 0);
    LDBH(0);
    LDA(1, 1);
    CVTW(0, 0);
    asm volatile("s_waitcnt lgkmcnt(0)" ::: "memory");
    __builtin_amdgcn_s_barrier();

    // ---- main loop (R12/R15-proven schedule, hh pass only) ----
#pragma unroll
    for (int t = 0; t < NT; ++t) {
        if (t + 2 < NT) LDA((t + 2) & 1, t + 2);

        f16x8 ahf[4];
#pragma unroll
        for (int m = 0; m < 4; ++m)
            ahf[m] = *(const f16x8*)(smem + (t & 1) * 4096 + fa + m * 1024);
        if (t + 1 < NT) CVTW((t + 1) & 1, (t + 1) & 1);
        asm volatile("s_waitcnt lgkmcnt(0)" ::: "memory");
        __builtin_amdgcn_s_barrier();

        __builtin_amdgcn_s_setprio(1);
#pragma unroll
        for (int m = 0; m < 4; ++m)
#pragma unroll
            for (int n = 0; n < 4; ++n)
                acc[m][n] = __builtin_amdgcn_mfma_f32_16x16x32_f16(ahf[m], bfh[n], acc[m][n], 0, 0, 0);
        __builtin_amdgcn_s_setprio(0);
        if (t + 1 < NT) LDBH(t + 1);
    }
    __syncthreads();

    // ---- epilogue overlays ----
    float* rowssq = (float*)(smem);                       // 256 B
    float* wvalp  = (float*)(smem + 256);                 // 1 KiB
    float* wsecp  = (float*)(smem + 1280);                // 1 KiB
    int*   wcolp  = (int*)(smem + 2304);                  // 1 KiB
    float* rowtop = (float*)(smem + 3328);                // 256 B
    float* rowinv = (float*)(smem + 3584);                // 256 B
    float* lrowS  = (float*)(smem + 3840);                // 256 B
    unsigned long long* fmaskS = (unsigned long long*)(smem + 4096); // 8 B
    int*   ccount = (int*)(smem + 4160);                  // 256 B
    int*   clist  = (int*)(smem + 4416);                  // 64*CAP*4 = 3072 B
    float* wrv    = (float*)(smem + 7488);                // 16 B
    int*   wrc    = (int*)(smem + 7552);                  // 16 B

    ssq += __shfl_xor(ssq, 1);
    ssq += __shfl_xor(ssq, 2);
    if (achk == 0) rowssq[arow] = ssq;

    // per-wave top-2 (R15-proven). acc[m][n][j]=S[16m+4g+j][64wv+16n+l15]
#pragma unroll
    for (int m = 0; m < 4; ++m) {
#pragma unroll
        for (int j = 0; j < 4; ++j) {
            float b0 = acc[m][0][j]; int i0 = 64*wv + l15; float s0 = -3.0e38f;
#pragma unroll
            for (int n = 1; n < 4; ++n) {
                float v = acc[m][n][j]; int c = 64*wv + 16*n + l15;
                if (v > b0) { s0 = b0; b0 = v; i0 = c; } else { s0 = fmaxf(s0, v); }
            }
#pragma unroll
            for (int off = 1; off < 16; off <<= 1) {
                float ov = __shfl_xor(b0, off);
                int   oi = __shfl_xor(i0, off);
                float os = __shfl_xor(s0, off);
                if (ov > b0 || (ov == b0 && oi < i0)) { s0 = fmaxf(os, b0); b0 = ov; i0 = oi; }
                else                                  { s0 = fmaxf(s0, ov); }
            }
            if (l15 == 0) {
                int r = 16*m + 4*g + j;
                wvalp[wv * BM + r] = b0; wsecp[wv * BM + r] = s0; wcolp[wv * BM + r] = i0;
            }
        }
    }
    __syncthreads();

    // combine 4 waves on wave 0; write unflagged outputs; build flag mask
    if (tid < BM) {
        int r = tid;
        if (r < 64) ccount[r] = 0;
        float b = wvalp[r], s = wsecp[r]; int i = wcolp[r];
#pragma unroll
        for (int w = 1; w < 4; ++w) {
            float bw = wvalp[w * BM + r], sw2 = wsecp[w * BM + r]; int iw = wcolp[w * BM + r];
            if (bw > b || (bw == b && iw < i)) { s = fmaxf(b, sw2); b = bw; i = iw; }
            else                               { s = fmaxf(s, bw); }
        }
        float inv = 1.f / fmaxf(sqrtf(rowssq[r]), EPS);
        rowtop[r] = b; rowinv[r] = inv;
        bool amb = (b - s) < DELTA;
        unsigned long long msk = __ballot(amb);
        int gr = row0 + r;
        if (!amb) {
            out[gr]        = (float)i;
            out[NTOT + gr] = (float)PA[i];
        }
        lrowS[r] = amb ? 0.f : -(b * inv) * W[gr];
        if (tid == 0) fmaskS[0] = msk;
    }
    __syncthreads();

    const unsigned long long fm = fmaskS[0];
    if (fm) {
        // candidate scan: STATIC acc walk (no runtime reg indexing)
#pragma unroll
        for (int m = 0; m < 4; ++m) {
#pragma unroll
            for (int j = 0; j < 4; ++j) {
                int r = 16*m + 4*g + j;
                if ((fm >> r) & 1ull) {
                    float th = rowtop[r] - DELTA;
#pragma unroll
                    for (int n = 0; n < 4; ++n) {
                        if (acc[m][n][j] >= th) {
                            int col = 64*wv + 16*n + l15;
                            int pos = atomicAdd(&ccount[r], 1);
                            if (pos < CAP) clist[r * CAP + pos] = col;
                        }
                    }
                }
            }
        }
        __syncthreads();

        // exact rescore per flagged row (uniform loop; coalesced wave-dots)
        unsigned long long mm = fm;
        while (mm) {
            int r = __ffsll((long long)mm) - 1;
            mm &= mm - 1;
            int cnt = ccount[r]; if (cnt > CAP) cnt = CAP;
            const float* arp = A + (size_t)(row0 + r) * DIM;
            float av6[6];
#pragma unroll
            for (int i2 = 0; i2 < 6; ++i2) av6[i2] = arp[i2*64 + lane];
            float bv = -3.0e38f; int bc2 = 0x7fffffff;
            for (int k = wv; k < cnt; k += 4) {
                int col = clist[r * CAP + k];
                const float* cp = cc + (size_t)col * DIM;
                float d = 0.f;
#pragma unroll
                for (int i2 = 0; i2 < 6; ++i2) d = fmaf(av6[i2], cp[i2*64 + lane], d);
#pragma unroll
                for (int off = 1; off < 64; off <<= 1) d += __shfl_xor(d, off);
                float val = d * invn[col];
                if (val > bv || (val == bv && col < bc2)) { bv = val; bc2 = col; }
            }
            if (lane == 0) { wrv[wv] = bv; wrc[wv] = bc2; }
            __syncthreads();
            if (tid == 0) {
                float b2 = wrv[0]; int c2 = wrc[0];
#pragma unroll
                for (int w = 1; w < 4; ++w) {
                    float ov = wrv[w]; int oc = wrc[w];
                    if (ov > b2 || (ov == b2 && oc < c2)) { b2 = ov; c2 = oc; }
                }
                int gr = row0 + r;
                out[gr]        = (float)c2;
                out[NTOT + gr] = (float)PA[c2];
                lrowS[r] = -(b2 * rowinv[r]) * W[gr];
            }
            __syncthreads();
        }
    }

    // deterministic block loss partial
    if (tid < BM) {
        float l = lrowS[tid];
#pragma unroll
        for (int off = 1; off < 64; off <<= 1) l += __shfl_xor(l, off);
        if (tid == 0) partial[blockIdx.x] = l;
    }
}

// ---------------------------------------------------------------------------
// Deterministic final loss reduction: 4096 partials -> mean
// ---------------------------------------------------------------------------
__global__ void loss_reduce(const float* __restrict__ partial, float* __restrict__ out_loss) {
    __shared__ float s[256];
    float v = 0.f;
    for (int i = threadIdx.x; i < GRID_MAIN; i += 256) v += partial[i];
    s[threadIdx.x] = v;
    __syncthreads();
    for (int off = 128; off >= 1; off >>= 1) {
        if ((int)threadIdx.x < off) s[threadIdx.x] += s[threadIdx.x + off];
        __syncthreads();
    }
    if (threadIdx.x == 0) out_loss[0] = s[0] * (1.0f / (float)NTOT);
}

extern "C" void kernel_launch(void* const* d_in, const int* in_sizes, int n_in,
                              void* d_out, int out_size, void* d_ws, size_t ws_size,
                              hipStream_t stream) {
    const float* features = (const float*)d_in[0];
    const float* weight   = (const float*)d_in[1];
    const float* cc       = (const float*)d_in[2];
    const int*   pa       = (const int*)d_in[3];
    float* out = (float*)d_out;

    _Float16* bh   = (_Float16*)d_ws;              // 192 KiB fragment-order hi
    float* invn    = (float*)(bh + KCL * DIM);     // 1 KiB
    float* partial = invn + KCL;                   // 16 KiB

    hipLaunchKernelGGL(prep_clusters, dim3(KCL), dim3(64), 0, stream, cc, bh, invn);
    hipLaunchKernelGGL(kmeans_main, dim3(GRID_MAIN), dim3(TBS), 0, stream,
                       features, weight, bh, cc, invn, pa, out, partial);
    hipLaunchKernelGGL(loss_reduce, dim3(1), dim3(256), 0, stream, partial, out + 2 * NTOT);
}

// Round 17
// 183.813 us; speedup vs baseline: 1.5415x; 1.1322x over previous
//
#include <hip/hip_runtime.h>
#include <hip/hip_bf16.h>

#define NTOT (4*256*256)      // 262144 feature rows
#define DIM 384
#define KCL 256               // clusters
#define BM 64                 // rows per block tile
#define TBS 256
#define GRID_MAIN (NTOT/BM)   // 4096 blocks
#define NT 12                 // K-steps of 32
#define EPS 1e-12f

// LDS: A double-buffer only. buf p at p*8192: hi +0, lo +4096. Total 16 KiB.
#define AB(p) ((p) * 8192)
#define SMEM_BYTES 16384

typedef __attribute__((ext_vector_type(8))) _Float16 f16x8;
typedef __attribute__((ext_vector_type(4))) float f32x4;

// ---------------------------------------------------------------------------
// Pre-pass: L2-normalize clusters; fp16 hi+lo residual in FRAGMENT ORDER:
// (j,d) -> ((((t*4+w)*4+n)*4+g)*16+nl)*8+d0  [proven R9-R16].
// ---------------------------------------------------------------------------
__global__ void prep_clusters(const float* __restrict__ cc,
                              _Float16* __restrict__ bh,
                              _Float16* __restrict__ bl) {
    int j = blockIdx.x, l = threadIdx.x;   // 256 blocks x 64 lanes
    float v[6]; float ssq = 0.f;
#pragma unroll
    for (int i = 0; i < 6; ++i) { v[i] = cc[j*DIM + l + 64*i]; ssq = fmaf(v[i], v[i], ssq); }
#pragma unroll
    for (int off = 32; off >= 1; off >>= 1) ssq += __shfl_xor(ssq, off);
    float inv = 1.f / fmaxf(sqrtf(ssq), EPS);
    const int w = j >> 6, n = (j >> 4) & 3, nl = j & 15;
#pragma unroll
    for (int i = 0; i < 6; ++i) {
        int d = l + 64 * i;
        float x = v[i] * inv;
        _Float16 h  = (_Float16)x;
        _Float16 lo = (_Float16)(x - (float)h);
        size_t idx = (size_t)((((((d >> 5)*4 + w)*4 + n)*4 + ((d >> 3) & 3))*16 + nl)*8
                              + (d & 7));
        bh[idx] = h;
        bl[idx] = lo;
    }
}

// ---------------------------------------------------------------------------
// Main: 3-pass split-fp16 MFMA GEMM, bit-identical numerics to R2-R6/R10-R14.
// R17 change vs R12 (the 182us best): A f32 prefetch issued at END of step,
// AFTER the B register loads, fenced with sched_barrier(0). vmcnt retires in
// order, so with B older than A the MFMA's B-wait is a counted vmcnt(2) that
// leaves the HBM A-loads in flight across the barrier (was: blanket wait that
// drained the HBM load every step). A prefetch depth 2 -> 3 (slot parity ok).
// ---------------------------------------------------------------------------
__global__ __launch_bounds__(TBS, 3)
void kmeans_main(const float* __restrict__ A,    // [NTOT][384] f32
                 const float* __restrict__ W,    // [NTOT]
                 const _Float16* __restrict__ Bh,// fragment-order fp16 hi
                 const _Float16* __restrict__ Bl,// fragment-order fp16 lo
                 const int*   __restrict__ PA,   // [256]
                 float* __restrict__ out,        // [2*NTOT+1]
                 float* __restrict__ partial)    // [GRID_MAIN]
{
    __shared__ unsigned char smem[SMEM_BYTES];

    const int tid  = threadIdx.x;
    const int wv   = tid >> 6;        // wave -> cluster quarter [64wv, 64wv+64)
    const int lane = tid & 63;
    const int g    = lane >> 4;
    const int l15  = lane & 15;
    const int sw   = (l15 >> 1) & 3;  // A read-side swizzle (proven 0-conflict)
    const int row0 = blockIdx.x * BM;
    const int arow = tid >> 2, achk = tid & 3;
    const int awb  = (((arow << 2) + (achk ^ ((arow >> 1) & 3))) << 4);
    const int fa   = l15 * 64 + ((g ^ sw) << 4);      // A frag base (+m*1024)

    const float* ap = A + (size_t)(row0 + arow) * DIM + achk * 8;
    const unsigned char* bsh = (const unsigned char*)Bh + (size_t)(wv * 4) * 1024 + lane * 16;
    const unsigned char* bsl = (const unsigned char*)Bl + (size_t)(wv * 4) * 1024 + lane * 16;

    f32x4 acc[4][4];
#pragma unroll
    for (int m = 0; m < 4; ++m)
#pragma unroll
        for (int n = 0; n < 4; ++n) acc[m][n] = (f32x4){0.f, 0.f, 0.f, 0.f};
    float ssq = 0.f;

    f16x8  bfh[4], bfl[4];       // current B fragments (registers, single set)
    float4 sA[2][2];             // A f32 prefetch slots by tile parity

    auto LDA = [&](int s, int tt) {
        sA[s][0] = *(const float4*)(ap + tt * 32);
        sA[s][1] = *(const float4*)(ap + tt * 32 + 4);
    };
    auto LDBH = [&](int tt) {
#pragma unroll
        for (int n = 0; n < 4; ++n)
            bfh[n] = *(const f16x8*)(bsh + (size_t)(tt * 16 + n) * 1024);
    };
    auto LDBL = [&](int tt) {
#pragma unroll
        for (int n = 0; n < 4; ++n)
            bfl[n] = *(const f16x8*)(bsl + (size_t)(tt * 16 + n) * 1024);
    };
    // split f32 tile (slot s) -> hi/lo fp16, swizzled ds_write to buf p
    auto CVTW = [&](int s, int p) {
        float av[8] = {sA[s][0].x, sA[s][0].y, sA[s][0].z, sA[s][0].w,
                       sA[s][1].x, sA[s][1].y, sA[s][1].z, sA[s][1].w};
        f16x8 h8, l8;
#pragma unroll
        for (int e = 0; e < 8; ++e) {
            _Float16 hh = (_Float16)av[e];
            h8[e] = hh;
            l8[e] = (_Float16)(av[e] - (float)hh);
            ssq = fmaf(av[e], av[e], ssq);
        }
        *(f16x8*)(smem + AB(p) + awb) = h8;
        *(f16x8*)(smem + AB(p) + 4096 + awb) = l8;
    };

    // ---- prologue: B(0) first (oldest), then A tiles 0,1,2 ----
    LDBL(0); LDBH(0);
    LDA(0, 0);                   // slot 0 <- tile 0
    CVTW(0, 0);                  // waits tile-0 loads; buf0 published below
    LDA(1, 1);                   // slot 1 <- tile 1
    LDA(0, 2);                   // slot 0 <- tile 2 (slot 0 freed by CVTW)
    asm volatile("s_waitcnt lgkmcnt(0)" ::: "memory");
    __builtin_amdgcn_s_barrier();

    // ---- main loop: fully unrolled; B-loads BEFORE A-loads each step ----
#pragma unroll
    for (int t = 0; t < NT; ++t) {
        // fragments of tile t from buf(t&1) (published at previous barrier)
        f16x8 ahf[4], alf[4];
#pragma unroll
        for (int m = 0; m < 4; ++m) {
            ahf[m] = *(const f16x8*)(smem + AB(t & 1) + fa + m * 1024);
            alf[m] = *(const f16x8*)(smem + AB(t & 1) + 4096 + fa + m * 1024);
        }
        if (t + 1 < NT) CVTW((t + 1) & 1, (t + 1) & 1);  // publish A(t+1) -> other buf
        asm volatile("s_waitcnt lgkmcnt(0)" ::: "memory");
        __builtin_amdgcn_s_barrier();

        // 3 passes, order identical to R2-R6 (bit-identical accumulation)
        __builtin_amdgcn_s_setprio(1);
#pragma unroll
        for (int m = 0; m < 4; ++m)
#pragma unroll
            for (int n = 0; n < 4; ++n)
                acc[m][n] = __builtin_amdgcn_mfma_f32_16x16x32_f16(ahf[m], bfh[n], acc[m][n], 0, 0, 0);
#pragma unroll
        for (int m = 0; m < 4; ++m)
#pragma unroll
            for (int n = 0; n < 4; ++n)
                acc[m][n] = __builtin_amdgcn_mfma_f32_16x16x32_f16(ahf[m], bfl[n], acc[m][n], 0, 0, 0);
        __builtin_amdgcn_s_setprio(0);
        if (t + 1 < NT) LDBL(t + 1);               // bfl dead after pass 2
        __builtin_amdgcn_s_setprio(1);
#pragma unroll
        for (int m = 0; m < 4; ++m)
#pragma unroll
            for (int n = 0; n < 4; ++n)
                acc[m][n] = __builtin_amdgcn_mfma_f32_16x16x32_f16(alf[m], bfh[n], acc[m][n], 0, 0, 0);
        __builtin_amdgcn_s_setprio(0);
        if (t + 1 < NT) LDBH(t + 1);               // bfh dead after pass 3

        // A prefetch LAST (younger than B in vmcnt order); depth-3.
        __builtin_amdgcn_sched_barrier(0);          // pin B-before-A issue order
        if (t + 3 < NT) LDA((t + 3) & 1, t + 3);   // slot freed by CVTW above
    }
    __syncthreads();   // full drain before overlaying smem

    // ---- epilogue (overlay scratch on smem; R5/R10-proven logic) ----
    float* rowssq = (float*)smem;                 // 256 B
    float* wvalp  = (float*)(smem + 256);         // 1 KiB
    int*   wcolp  = (int*)(smem + 1280);          // 1 KiB

    ssq += __shfl_xor(ssq, 1);
    ssq += __shfl_xor(ssq, 2);
    if (achk == 0) rowssq[arow] = ssq;

    // per-row argmax. acc[m][n][j] = S[16m + 4g + j][64wv + 16n + l15]
#pragma unroll
    for (int m = 0; m < 4; ++m) {
#pragma unroll
        for (int j = 0; j < 4; ++j) {
            float best = acc[m][0][j];
            int   bc   = 64*wv + l15;
#pragma unroll
            for (int n = 1; n < 4; ++n) {
                float v = acc[m][n][j];
                int   c = 64*wv + 16*n + l15;
                if (v > best) { best = v; bc = c; }
            }
#pragma unroll
            for (int off = 1; off < 16; off <<= 1) {
                float ov = __shfl_xor(best, off);
                int   oc = __shfl_xor(bc, off);
                if (ov > best || (ov == best && oc < bc)) { best = ov; bc = oc; }
            }
            if (l15 == 0) {
                wvalp[wv * BM + 16*m + 4*g + j] = best;
                wcolp[wv * BM + 16*m + 4*g + j] = bc;
            }
        }
    }
    __syncthreads();

    if (tid < BM) {
        int r = tid;
        float best = wvalp[r]; int bc = wcolp[r];
#pragma unroll
        for (int w = 1; w < 4; ++w) {
            float ov = wvalp[w * BM + r]; int oc = wcolp[w * BM + r];
            if (ov > best || (ov == best && oc < bc)) { best = ov; bc = oc; }
        }
        float inv = 1.f / fmaxf(sqrtf(rowssq[r]), EPS);
        int gr = row0 + r;
        out[gr]        = (float)bc;
        out[NTOT + gr] = (float)PA[bc];
        float lsum = -(best * inv) * W[gr];
#pragma unroll
        for (int off = 32; off >= 1; off >>= 1) lsum += __shfl_xor(lsum, off);
        if (tid == 0) partial[blockIdx.x] = lsum;
    }
}

// ---------------------------------------------------------------------------
// Deterministic final loss reduction: 4096 partials -> mean
// ---------------------------------------------------------------------------
__global__ void loss_reduce(const float* __restrict__ partial, float* __restrict__ out_loss) {
    __shared__ float s[256];
    float v = 0.f;
    for (int i = threadIdx.x; i < GRID_MAIN; i += 256) v += partial[i];
    s[threadIdx.x] = v;
    __syncthreads();
    for (int off = 128; off >= 1; off >>= 1) {
        if ((int)threadIdx.x < off) s[threadIdx.x] += s[threadIdx.x + off];
        __syncthreads();
    }
    if (threadIdx.x == 0) out_loss[0] = s[0] * (1.0f / (float)NTOT);
}

extern "C" void kernel_launch(void* const* d_in, const int* in_sizes, int n_in,
                              void* d_out, int out_size, void* d_ws, size_t ws_size,
                              hipStream_t stream) {
    const float* features = (const float*)d_in[0];
    const float* weight   = (const float*)d_in[1];
    const float* cc       = (const float*)d_in[2];
    const int*   pa       = (const int*)d_in[3];
    float* out = (float*)d_out;

    _Float16* bh   = (_Float16*)d_ws;              // 192 KiB fragment-order hi
    _Float16* bl   = bh + KCL * DIM;               // 192 KiB fragment-order lo
    float* partial = (float*)(bl + KCL * DIM);     // 16 KiB

    hipLaunchKernelGGL(prep_clusters, dim3(KCL), dim3(64), 0, stream, cc, bh, bl);
    hipLaunchKernelGGL(kmeans_main, dim3(GRID_MAIN), dim3(TBS), 0, stream,
                       features, weight, bh, bl, pa, out, partial);
    hipLaunchKernelGGL(loss_reduce, dim3(1), dim3(256), 0, stream, partial, out + 2 * NTOT);
}